// Round 3
// baseline (203.263 us; speedup 1.0000x reference)
//
#include <hip/hip_runtime.h>

#define EDIM 128
#define MDIM 8
#define ADIM 64
#define NFR  50
#define NCOL (NFR * MDIM)   // 400
#define NSLICE 64           // contention slices for softmax denominator atomics

typedef __attribute__((ext_vector_type(8))) short short8;
typedef __attribute__((ext_vector_type(4))) float f32x4;

// counted vmcnt wait (T4): literal N, fence compiler reordering after it
#define WAITVM(N) do { asm volatile("s_waitcnt vmcnt(" #N ")" ::: "memory"); \
                       __builtin_amdgcn_sched_barrier(0); } while (0)

// async global->LDS, 16B per lane; global addr per-lane, LDS dest uniform base
__device__ __forceinline__ void asyncStage16(const void* g, void* l) {
    __builtin_amdgcn_global_load_lds(
        (const __attribute__((address_space(1))) void*)g,
        (__attribute__((address_space(3))) void*)l, 16, 0, 0);
}

__device__ __forceinline__ float waveReduceSum(float v) {
    #pragma unroll
    for (int s = 32; s >= 1; s >>= 1) v += __shfl_xor(v, s, 64);
    return v;
}
__device__ __forceinline__ short f2bf(float x) {
    unsigned u = __float_as_uint(x);
    u += 0x7FFFu + ((u >> 16) & 1u);
    return (short)(u >> 16);
}
__device__ __forceinline__ float bf2f(short s) {
    return __uint_as_float(((unsigned)(unsigned short)s) << 16);
}
// Swizzled A-frag layout (proven). Block (Mt=r>>4, Kt=e>>5) of 512 shorts;
// within it slot = (q*16+(r&15)) ^ (q<<1), q=(e>>3)&3.
__device__ __forceinline__ int fragOff(int r, int e) {   // e multiple of 8
    int q = (e >> 3) & 3;
    int slot = (q * 16 + (r & 15)) ^ (q << 1);
    int block = ((r >> 4) << 2) | (e >> 5);
    return (block * 64 + slot) * 8;
}
__device__ __forceinline__ int slotR(int l) { return l ^ (((l >> 4) & 3) << 1); }

// rawFe row swizzle: LDS byte (f*512 + x) holds global row byte (x ^ ((f&7)<<4)).
// Applied on the global source at stage time, inverted (same XOR) on read.

// k0: pre-pack WA (B-frags 4Nt x 4Kt) and Key (4Kt, N padded 8->16 with 0);
// also zero the softmax-denominator slices (harness poisons ws each iter).
__global__ __launch_bounds__(256)
void k0_prep(const float* __restrict__ WA, const float* __restrict__ Key,
             short* __restrict__ WAfrag, short* __restrict__ Keyfrag,
             float* __restrict__ Ssum)
{
    int t = blockIdx.x * 256 + threadIdx.x;
    for (int i = t; i < NSLICE * NCOL; i += 5 * 256) Ssum[i] = 0.f;
    if (t < 1024) {
        int lane = t & 63;
        int Kt = (t >> 6) & 3;
        int Nt = t >> 8;
        int n  = Nt * 16 + (lane & 15);
        int k0 = Kt * 32 + (lane >> 4) * 8;
        short8 v;
        #pragma unroll
        for (int j = 0; j < 8; ++j) v[j] = f2bf(WA[(size_t)(k0 + j) * ADIM + n]);
        *(short8*)(WAfrag + (size_t)t * 8) = v;
    } else if (t < 1280) {
        int i = t - 1024;
        int lane = i & 63;
        int Kt = i >> 6;
        int n  = lane & 15;
        int k0 = Kt * 32 + (lane >> 4) * 8;
        short8 v;
        #pragma unroll
        for (int j = 0; j < 8; ++j)
            v[j] = (n < MDIM) ? f2bf(Key[(size_t)(k0 + j) * MDIM + n]) : (short)0;
        *(short8*)(Keyfrag + (size_t)i * 8) = v;
    }
}

// k1: one wave per b. Stage all 50 friend rows via global_load_lds (25 KB in
// flight), build MFMA A-frags in REGISTERS from staged LDS (no crossF),
// counted vmcnt per 16-row tile. LDS 26KB -> 6 blocks/CU.
__global__ __launch_bounds__(64)
void k1_attkey(const int* __restrict__ input_u, const int* __restrict__ input_uf,
               const float* __restrict__ uidW, const short* __restrict__ Keyfrag,
               float* __restrict__ att_key, float* __restrict__ Ssum,
               int user_num)
{
    __shared__ float rawFe[NFR * EDIM];   // 25.6 KB, swizzled rows
    __shared__ float uidn[EDIM];          // 512 B
    const int l = threadIdx.x;
    const int b = blockIdx.x;

    // ---- region 1: every global load issued (and fenced) before staging ----
    const int u = input_u[b];
    int ufv = (l < NFR) ? input_uf[(size_t)b * NFR + l] : user_num;
    float x0 = uidW[(size_t)u * EDIM + l];
    float x1 = uidW[(size_t)u * EDIM + 64 + l];
    short8 kb[4];
    #pragma unroll
    for (int Kt = 0; Kt < 4; ++Kt)
        kb[Kt] = *(const short8*)(Keyfrag + (size_t)(Kt * 64 + l) * 8);

    float s = waveReduceSum(x0 * x0 + x1 * x1);
    float uinv = 1.0f / fmaxf(sqrtf(s), 1e-12f);
    uidn[l] = x0 * uinv;
    uidn[64 + l] = x1 * uinv;
    __builtin_amdgcn_wave_barrier();

    asm volatile("s_waitcnt vmcnt(0)" ::: "memory");
    __builtin_amdgcn_sched_barrier(0);

    // ---- stage 50 rows, 2 rows per instruction, swizzled source ----
    {
        const int half = l >> 5, i = l & 31;
        #pragma unroll
        for (int c = 0; c < 25; ++c) {
            int f = 2 * c + half;
            int fid = __shfl(ufv, f, 64);
            const char* g = (const char*)(uidW + (size_t)fid * EDIM)
                          + ((i * 16) ^ ((f & 7) << 4));
            asyncStage16(g, (char*)rawFe + c * 1024);
        }
    }
    __builtin_amdgcn_sched_barrier(0);

    const int ko = (l >> 4) * 8;
    float4 unA[4], unB[4];
    #pragma unroll
    for (int Kt = 0; Kt < 4; ++Kt) {
        unA[Kt] = *(const float4*)&uidn[Kt * 32 + ko];
        unB[Kt] = *(const float4*)&uidn[Kt * 32 + ko + 4];
    }

    const int fr = l & 15;
    f32x4 accM[4];

    auto doMt = [&](int Mt) {
        int f = Mt * 16 + fr;
        int fc = (f < NFR) ? f : 0;          // clamp pad rows into bounds
        int sw = (fc & 7) << 4;
        const char* rp = (const char*)rawFe + fc * 512;
        float4 fea[4], feb[4];
        #pragma unroll
        for (int Kt = 0; Kt < 4; ++Kt) {
            int base = Kt * 128 + (l >> 4) * 32;
            fea[Kt] = *(const float4*)(rp + (base ^ sw));
            feb[Kt] = *(const float4*)(rp + ((base + 16) ^ sw));
        }
        float fss = 0.f;
        #pragma unroll
        for (int Kt = 0; Kt < 4; ++Kt)
            fss += fea[Kt].x*fea[Kt].x + fea[Kt].y*fea[Kt].y
                 + fea[Kt].z*fea[Kt].z + fea[Kt].w*fea[Kt].w
                 + feb[Kt].x*feb[Kt].x + feb[Kt].y*feb[Kt].y
                 + feb[Kt].z*feb[Kt].z + feb[Kt].w*feb[Kt].w;
        fss += __shfl_xor(fss, 16, 64);      // 4 lanes share a row (l&15 const)
        fss += __shfl_xor(fss, 32, 64);
        int fid = __shfl(ufv, fc, 64);
        float fn = (f < NFR && fid != user_num) ? 1.f : 0.f;
        float inv = fn / fmaxf(sqrtf(fss), 1e-12f);   // mask folded into inv
        f32x4 acc = {0.f, 0.f, 0.f, 0.f};
        #pragma unroll
        for (int Kt = 0; Kt < 4; ++Kt) {
            short8 a;
            a[0] = f2bf(unA[Kt].x * fea[Kt].x * inv);
            a[1] = f2bf(unA[Kt].y * fea[Kt].y * inv);
            a[2] = f2bf(unA[Kt].z * fea[Kt].z * inv);
            a[3] = f2bf(unA[Kt].w * fea[Kt].w * inv);
            a[4] = f2bf(unB[Kt].x * feb[Kt].x * inv);
            a[5] = f2bf(unB[Kt].y * feb[Kt].y * inv);
            a[6] = f2bf(unB[Kt].z * feb[Kt].z * inv);
            a[7] = f2bf(unB[Kt].w * feb[Kt].w * inv);
            acc = __builtin_amdgcn_mfma_f32_16x16x32_bf16(a, kb[Kt], acc, 0, 0, 0);
        }
        accM[Mt] = acc;
    };
    WAITVM(17); doMt(0);
    WAITVM(9);  doMt(1);
    WAITVM(1);  doMt(2);
    WAITVM(0);  doMt(3);

    // all staging retired -> stores/atomics free to issue
    if (fr < MDIM) {
        float* Ss = Ssum + (size_t)(b & (NSLICE - 1)) * NCOL;
        #pragma unroll
        for (int Mt = 0; Mt < 4; ++Mt) {
            const int fbase = Mt * 16 + (l >> 4) * 4;
            #pragma unroll
            for (int r = 0; r < 4; ++r) {
                int f = fbase + r;
                if (f < NFR) {
                    att_key[((size_t)b * NFR + f) * MDIM + fr] = accM[Mt][r];
                    // masked rows have acc==0 -> exp(0)=1, matching reference
                    // softmax(axis=0) denominator semantics
                    atomicAdd(&Ss[f * MDIM + fr], __expf(accM[Mt][r]));
                }
            }
        }
    }
}

// k2b: merge NSLICE partials per column -> inv denominator
__global__ __launch_bounds__(256)
void k2b_merge(const float* __restrict__ Ssum, float* __restrict__ ise)
{
    int col = blockIdx.x * 256 + threadIdx.x;
    if (col >= NCOL) return;
    float S = 0.f;
    #pragma unroll
    for (int s = 0; s < NSLICE; ++s) S += Ssum[s * NCOL + col];
    ise[col] = 1.0f / S;
}

// k3: one wave per b. Stage friend rows async; amL/Mem loaded+consumed before
// the fence; f2 frag -> 64 MFMAs -> fold -> j -> friend sum -> score.
// LDS 47KB -> 3 blocks/CU, 75KB staged bytes in flight per CU.
__global__ __launch_bounds__(64)
void k3_final(const int* __restrict__ input_u, const int* __restrict__ input_i,
              const int* __restrict__ input_uf, const float* __restrict__ uidW,
              const float* __restrict__ iidW, const float* __restrict__ i_bias,
              const float* __restrict__ Mem, const short* __restrict__ WAfrag,
              const float* __restrict__ BA, const float* __restrict__ U_omega,
              const float* __restrict__ att_key, const float* __restrict__ ise,
              float* __restrict__ out, int user_num)
{
    __shared__ float rawFe[NFR * EDIM];   // 25.6 KB, swizzled rows
    __shared__ short f2F[64 * EDIM];      // 16 KB
    __shared__ float amL[NCOL];           // 1.6 KB
    __shared__ float MemL[MDIM * EDIM];   // 4 KB
    __shared__ float jxL[64];
    const int l = threadIdx.x;
    const int b = blockIdx.x;

    // ---- region 1: every global load issued+consumed before the fence ----
    const int u = input_u[b];
    const int ii = input_i[b];
    const float ib = i_bias[ii];
    int ufv = (l < NFR) ? input_uf[(size_t)b * NFR + l] : user_num;

    float akv[7], isv[7];
    #pragma unroll
    for (int c = 0; c < 7; ++c) {
        int i = l + 64 * c;
        if (i < NCOL) { akv[c] = att_key[(size_t)b * NCOL + i]; isv[c] = ise[i]; }
    }
    #pragma unroll
    for (int c = 0; c < 2; ++c) {
        int i = l + 64 * c;               // 128 chunks of 4 floats
        float4 v = *(const float4*)&Mem[i * 4];
        *(float4*)&MemL[i * 4] = v;
    }
    #pragma unroll
    for (int c = 0; c < 7; ++c) {
        int i = l + 64 * c;
        if (i < NCOL) {
            int fid = __shfl(ufv, i >> 3, 64);
            amL[i] = (fid != user_num) ? __expf(akv[c]) * isv[c] : 0.f;
        }
    }
    __builtin_amdgcn_wave_barrier();

    asm volatile("s_waitcnt vmcnt(0)" ::: "memory");
    __builtin_amdgcn_sched_barrier(0);

    // ---- stage 50 friend rows (only staging ops in the vmcnt queue now) ----
    {
        const int half = l >> 5, i = l & 31;
        #pragma unroll
        for (int c = 0; c < 25; ++c) {
            int f = 2 * c + half;
            int fid = __shfl(ufv, f, 64);
            const char* g = (const char*)(uidW + (size_t)fid * EDIM)
                          + ((i * 16) ^ ((f & 7) << 4));
            asyncStage16(g, (char*)rawFe + c * 1024);
        }
    }
    __builtin_amdgcn_sched_barrier(0);

    const int kg = l & 15, fl = l >> 4;
    const int e0 = kg * 8;
    float4 mAv[MDIM], mBv[MDIM];          // Mem slice from LDS (hoisted)
    #pragma unroll
    for (int m = 0; m < MDIM; ++m) {
        mAv[m] = *(const float4*)&MemL[m * EDIM + e0];
        mBv[m] = *(const float4*)&MemL[m * EDIM + e0 + 4];
    }

    // phase 1: f2 = (am x Mem) * fe -> swizzled frag, counted-vmcnt chunks
    auto doIt = [&](int it) {
        int f = fl + 4 * it;
        short8 outv = {0, 0, 0, 0, 0, 0, 0, 0};
        if (f < NFR) {
            int sw = (f & 7) << 4;
            const char* rp = (const char*)rawFe + f * 512;
            float4 g0 = *(const float4*)(rp + ((e0 * 4) ^ sw));
            float4 g1 = *(const float4*)(rp + ((e0 * 4 + 16) ^ sw));
            float4 am0 = *(const float4*)&amL[f * 8];
            float4 am1 = *(const float4*)&amL[f * 8 + 4];
            float4 fa = {0.f, 0.f, 0.f, 0.f}, fb = {0.f, 0.f, 0.f, 0.f};
            #pragma unroll
            for (int m = 0; m < 4; ++m) {
                float c0 = (&am0.x)[m], c1 = (&am1.x)[m];
                fa.x += c0 * mAv[m].x + c1 * mAv[m + 4].x;
                fa.y += c0 * mAv[m].y + c1 * mAv[m + 4].y;
                fa.z += c0 * mAv[m].z + c1 * mAv[m + 4].z;
                fa.w += c0 * mAv[m].w + c1 * mAv[m + 4].w;
                fb.x += c0 * mBv[m].x + c1 * mBv[m + 4].x;
                fb.y += c0 * mBv[m].y + c1 * mBv[m + 4].y;
                fb.z += c0 * mBv[m].z + c1 * mBv[m + 4].z;
                fb.w += c0 * mBv[m].w + c1 * mBv[m + 4].w;
            }
            // masked friends: am==0 -> fa=fb=0 -> f2=0 (matches reference)
            outv[0] = f2bf(fa.x * g0.x);
            outv[1] = f2bf(fa.y * g0.y);
            outv[2] = f2bf(fa.z * g0.z);
            outv[3] = f2bf(fa.w * g0.w);
            outv[4] = f2bf(fb.x * g1.x);
            outv[5] = f2bf(fb.y * g1.y);
            outv[6] = f2bf(fb.z * g1.z);
            outv[7] = f2bf(fb.w * g1.w);
        }
        *(short8*)&f2F[fragOff(f, e0)] = outv;
    };
    WAITVM(17); doIt(0);  doIt(1);  doIt(2);  doIt(3);
    WAITVM(9);  doIt(4);  doIt(5);  doIt(6);  doIt(7);
    WAITVM(1);  doIt(8);  doIt(9);  doIt(10); doIt(11);
    WAITVM(0);  doIt(12); doIt(13); doIt(14); doIt(15);
    __builtin_amdgcn_wave_barrier();

    // phase 2: h = f2(64x128) x WA(128x64), 64 MFMAs
    const int sl = slotR(l);
    f32x4 acc[4][4];
    #pragma unroll
    for (int Mt = 0; Mt < 4; ++Mt)
        #pragma unroll
        for (int Nt = 0; Nt < 4; ++Nt) acc[Mt][Nt] = (f32x4){0.f, 0.f, 0.f, 0.f};
    #pragma unroll
    for (int Kt = 0; Kt < 4; ++Kt) {
        short8 a[4];
        #pragma unroll
        for (int Mt = 0; Mt < 4; ++Mt)
            a[Mt] = *(const short8*)&f2F[(((Mt << 2) | Kt) * 64 + sl) * 8];
        #pragma unroll
        for (int Nt = 0; Nt < 4; ++Nt) {
            short8 bf = *(const short8*)(WAfrag + (size_t)(((Nt << 2) | Kt) * 64 + l) * 8);
            #pragma unroll
            for (int Mt = 0; Mt < 4; ++Mt)
                acc[Mt][Nt] = __builtin_amdgcn_mfma_f32_16x16x32_bf16(a[Mt], bf, acc[Mt][Nt], 0, 0, 0);
        }
    }

    // phase 3: fold relu(h+BA)*U_omega over all 64 cols -> per-friend p
    float ba4[4], uo4[4];
    #pragma unroll
    for (int Nt = 0; Nt < 4; ++Nt) {
        ba4[Nt] = BA[Nt * 16 + kg];
        uo4[Nt] = U_omega[Nt * 16 + kg];
    }
    float v[16];
    #pragma unroll
    for (int Mt = 0; Mt < 4; ++Mt)
        #pragma unroll
        for (int r = 0; r < 4; ++r) {
            float sv = 0.f;
            #pragma unroll
            for (int Nt = 0; Nt < 4; ++Nt)
                sv += fmaxf(acc[Mt][Nt][r] + ba4[Nt], 0.f) * uo4[Nt];
            v[Mt * 4 + r] = sv;
        }

    const bool c0 = l & 1, c1 = l & 2, c2 = l & 4, c3 = l & 8;
    #pragma unroll
    for (int k = 0; k < 8; ++k) {
        float lo = v[k], hi = v[k + 8];
        float send = c0 ? lo : hi;
        float recv = __shfl_xor(send, 1, 64);
        v[k] = c0 ? (hi + recv) : (lo + recv);
    }
    #pragma unroll
    for (int k = 0; k < 4; ++k) {
        float lo = v[k], hi = v[k + 4];
        float send = c1 ? lo : hi;
        float recv = __shfl_xor(send, 2, 64);
        v[k] = c1 ? (hi + recv) : (lo + recv);
    }
    #pragma unroll
    for (int k = 0; k < 2; ++k) {
        float lo = v[k], hi = v[k + 2];
        float send = c2 ? lo : hi;
        float recv = __shfl_xor(send, 4, 64);
        v[k] = c2 ? (hi + recv) : (lo + recv);
    }
    {
        float lo = v[0], hi = v[1];
        float send = c3 ? lo : hi;
        float recv = __shfl_xor(send, 8, 64);
        v[0] = c3 ? (hi + recv) : (lo + recv);
    }
    const int vIdx = ((l & 1) << 3) | ((l & 2) << 1) | ((l & 4) >> 1) | ((l & 8) >> 3);
    const int fLane = (vIdx >> 2) * 16 + (l >> 4) * 4 + (vIdx & 3);

    int ufF = __shfl(ufv, fLane, 64);
    float jv = 0.f;
    if (fLane < NFR && ufF != user_num) jv = __expf(v[0]);
    jxL[fLane] = jv;
    float winv = 1.0f / (waveReduceSum(jv) + 1e-8f);
    __builtin_amdgcn_wave_barrier();

    // phase 4: friend-weighted sum of f2 (pad rows are zero, jx pad = 0)
    float pa[8] = {0.f, 0.f, 0.f, 0.f, 0.f, 0.f, 0.f, 0.f};
    #pragma unroll 4
    for (int it = 0; it < 16; ++it) {
        int f = fl + 4 * it;
        float jf = jxL[f];
        short8 vv = *(const short8*)&f2F[fragOff(f, e0)];
        #pragma unroll
        for (int j = 0; j < 8; ++j) pa[j] += jf * bf2f(vv[j]);
    }
    #pragma unroll
    for (int j = 0; j < 8; ++j) {
        pa[j] += __shfl_xor(pa[j], 16, 64);
        pa[j] += __shfl_xor(pa[j], 32, 64);
    }

    // epilogue: score = sum_e (uid+friend)*iid + i_bias (4x duplicated -> *0.25)
    const float* up = uidW + (size_t)u * EDIM + e0;
    const float* ip = iidW + (size_t)ii * EDIM + e0;
    float4 u0 = *(const float4*)up;
    float4 u1 = *(const float4*)(up + 4);
    float4 i0 = *(const float4*)ip;
    float4 i1 = *(const float4*)(ip + 4);
    float sc = 0.f;
    #pragma unroll
    for (int j = 0; j < 4; ++j) {
        sc += ((&u0.x)[j] + pa[j] * winv) * (&i0.x)[j];
        sc += ((&u1.x)[j] + pa[j + 4] * winv) * (&i1.x)[j];
    }
    float red = waveReduceSum(sc);
    if (l == 0) out[b] = red * 0.25f + ib;
}

extern "C" void kernel_launch(void* const* d_in, const int* in_sizes, int n_in,
                              void* d_out, int out_size, void* d_ws, size_t ws_size,
                              hipStream_t stream)
{
    const int*   input_u  = (const int*)d_in[0];
    const int*   input_i  = (const int*)d_in[1];
    const int*   input_uf = (const int*)d_in[2];
    const float* uidW     = (const float*)d_in[3];
    const float* iidW     = (const float*)d_in[4];
    const float* i_bias   = (const float*)d_in[5];
    const float* Key      = (const float*)d_in[6];
    const float* Mem      = (const float*)d_in[7];
    const float* WA       = (const float*)d_in[8];
    const float* BA       = (const float*)d_in[9];
    const float* U_om     = (const float*)d_in[10];

    const int B = in_sizes[0];
    const int user_num = in_sizes[3] / EDIM - 1;

    float* att  = (float*)d_ws;                                  // B*400
    float* Ssum = att + (size_t)B * NCOL;                        // 64*400
    float* ise  = Ssum + NSLICE * NCOL;                          // 400
    short* WAfrag  = (short*)(ise + NCOL);                       // 8192
    short* Keyfrag = WAfrag + 4 * 4 * 64 * 8;                    // 2048

    k0_prep<<<5, 256, 0, stream>>>(WA, Key, WAfrag, Keyfrag, Ssum);
    k1_attkey<<<B, 64, 0, stream>>>(input_u, input_uf, uidW, Keyfrag, att,
                                    Ssum, user_num);
    k2b_merge<<<2, 256, 0, stream>>>(Ssum, ise);
    k3_final<<<B, 64, 0, stream>>>(input_u, input_i, input_uf, uidW, iidW, i_bias,
                                   Mem, WAfrag, BA, U_om, att, ise,
                                   (float*)d_out, user_num);
}

// Round 4
// 173.008 us; speedup vs baseline: 1.1749x; 1.1749x over previous
//
#include <hip/hip_runtime.h>

#define EDIM 128
#define MDIM 8
#define ADIM 64
#define NFR  50
#define NCOL (NFR * MDIM)   // 400
#define NSLICE 64           // contention slices for softmax denominator atomics

typedef __attribute__((ext_vector_type(8))) short short8;
typedef __attribute__((ext_vector_type(4))) float f32x4;

__device__ __forceinline__ float waveReduceSum(float v) {
    #pragma unroll
    for (int s = 32; s >= 1; s >>= 1) v += __shfl_xor(v, s, 64);
    return v;
}
__device__ __forceinline__ short f2bf(float x) {
    unsigned u = __float_as_uint(x);
    u += 0x7FFFu + ((u >> 16) & 1u);
    return (short)(u >> 16);
}
__device__ __forceinline__ float bf2f(short s) {
    return __uint_as_float(((unsigned)(unsigned short)s) << 16);
}
// Swizzled A-frag layout (k3 only). Block (Mt=r>>4, Kt=e>>5) of 512 shorts;
// within it slot = (q*16+(r&15)) ^ (q<<1), q=(e>>3)&3.
__device__ __forceinline__ int fragOff(int r, int e) {   // e multiple of 8
    int q = (e >> 3) & 3;
    int slot = (q * 16 + (r & 15)) ^ (q << 1);
    int block = ((r >> 4) << 2) | (e >> 5);
    return (block * 64 + slot) * 8;
}
__device__ __forceinline__ int slotR(int l) { return l ^ (((l >> 4) & 3) << 1); }

// k0: pre-pack WA (B-frags 4Nt x 4Kt) and Key (4Kt, N padded 8->16 with 0);
// also zero the softmax-denominator slices (harness poisons ws each iter).
__global__ __launch_bounds__(256)
void k0_prep(const float* __restrict__ WA, const float* __restrict__ Key,
             short* __restrict__ WAfrag, short* __restrict__ Keyfrag,
             float* __restrict__ Ssum)
{
    int t = blockIdx.x * 256 + threadIdx.x;
    for (int i = t; i < NSLICE * NCOL; i += 5 * 256) Ssum[i] = 0.f;
    if (t < 1024) {
        int lane = t & 63;
        int Kt = (t >> 6) & 3;
        int Nt = t >> 8;
        int n  = Nt * 16 + (lane & 15);
        int k0 = Kt * 32 + (lane >> 4) * 8;
        short8 v;
        #pragma unroll
        for (int j = 0; j < 8; ++j) v[j] = f2bf(WA[(size_t)(k0 + j) * ADIM + n]);
        *(short8*)(WAfrag + (size_t)t * 8) = v;
    } else if (t < 1280) {
        int i = t - 1024;
        int lane = i & 63;
        int Kt = i >> 6;
        int n  = lane & 15;
        int k0 = Kt * 32 + (lane >> 4) * 8;
        short8 v;
        #pragma unroll
        for (int j = 0; j < 8; ++j)
            v[j] = (n < MDIM) ? f2bf(Key[(size_t)(k0 + j) * MDIM + n]) : (short)0;
        *(short8*)(Keyfrag + (size_t)i * 8) = v;
    }
}

// k1: one wave per b, ZERO staging LDS. A-frag = raw fe (bf16) gathered
// per-lane directly into registers; uid_n folded into B (Key'); 1/||fe|| and
// the friend mask applied to the MFMA OUTPUT rows. No barriers, ~0.75KB LDS.
__global__ __launch_bounds__(64)
void k1_attkey(const int* __restrict__ input_u, const int* __restrict__ input_uf,
               const float* __restrict__ uidW, const short* __restrict__ Keyfrag,
               float* __restrict__ att_key, float* __restrict__ Ssum,
               int user_num)
{
    __shared__ float uidn[EDIM];   // 512 B
    __shared__ float invL[64];     // 256 B
    const int l = threadIdx.x;
    const int b = blockIdx.x;

    const int u = input_u[b];
    int ufv = (l < NFR) ? input_uf[(size_t)b * NFR + l] : user_num;
    float x0 = uidW[(size_t)u * EDIM + l];
    float x1 = uidW[(size_t)u * EDIM + 64 + l];

    // friend ids for my 4 A-frag rows: f = Mt*16 + (l&15)
    // (rows 50..63 resolve to the zero-padded uidW row user_num; their MFMA
    //  output rows are discarded, so garbage there is harmless)
    int fid[4];
    #pragma unroll
    for (int Mt = 0; Mt < 4; ++Mt)
        fid[Mt] = __shfl(ufv, Mt * 16 + (l & 15), 64);
    const int eo = (l >> 4) * 8;    // my k-octet within each 32-wide K block

    // uid L2-normalize (independent of the gathers; overlaps with them)
    float s = waveReduceSum(x0 * x0 + x1 * x1);
    float uinv = 1.0f / fmaxf(sqrtf(s), 1e-12f);
    uidn[l] = x0 * uinv;
    uidn[64 + l] = x1 * uinv;
    __builtin_amdgcn_wave_barrier();

    f32x4 acc[4];
    #pragma unroll
    for (int Mt = 0; Mt < 4; ++Mt) acc[Mt] = (f32x4){0.f, 0.f, 0.f, 0.f};
    float fss[4] = {0.f, 0.f, 0.f, 0.f};

    #pragma unroll
    for (int Kt = 0; Kt < 4; ++Kt) {
        // gather my 4 rows' e-octets for this K block (8 b128 loads in flight)
        float4 ga[4], gb[4];
        #pragma unroll
        for (int Mt = 0; Mt < 4; ++Mt) {
            const float* fp = uidW + (size_t)fid[Mt] * EDIM + Kt * 32 + eo;
            ga[Mt] = *(const float4*)fp;
            gb[Mt] = *(const float4*)(fp + 4);
        }
        // B-frag: Key' = uid_n * Key for my k-octet
        short8 kb = *(const short8*)(Keyfrag + (size_t)(Kt * 64 + l) * 8);
        float4 un0 = *(const float4*)&uidn[Kt * 32 + eo];
        float4 un1 = *(const float4*)&uidn[Kt * 32 + eo + 4];
        short8 kbp;
        kbp[0] = f2bf(un0.x * bf2f(kb[0]));
        kbp[1] = f2bf(un0.y * bf2f(kb[1]));
        kbp[2] = f2bf(un0.z * bf2f(kb[2]));
        kbp[3] = f2bf(un0.w * bf2f(kb[3]));
        kbp[4] = f2bf(un1.x * bf2f(kb[4]));
        kbp[5] = f2bf(un1.y * bf2f(kb[5]));
        kbp[6] = f2bf(un1.z * bf2f(kb[6]));
        kbp[7] = f2bf(un1.w * bf2f(kb[7]));
        #pragma unroll
        for (int Mt = 0; Mt < 4; ++Mt) {
            fss[Mt] += ga[Mt].x*ga[Mt].x + ga[Mt].y*ga[Mt].y
                     + ga[Mt].z*ga[Mt].z + ga[Mt].w*ga[Mt].w
                     + gb[Mt].x*gb[Mt].x + gb[Mt].y*gb[Mt].y
                     + gb[Mt].z*gb[Mt].z + gb[Mt].w*gb[Mt].w;
            short8 a;
            a[0] = f2bf(ga[Mt].x); a[1] = f2bf(ga[Mt].y);
            a[2] = f2bf(ga[Mt].z); a[3] = f2bf(ga[Mt].w);
            a[4] = f2bf(gb[Mt].x); a[5] = f2bf(gb[Mt].y);
            a[6] = f2bf(gb[Mt].z); a[7] = f2bf(gb[Mt].w);
            acc[Mt] = __builtin_amdgcn_mfma_f32_16x16x32_bf16(a, kbp, acc[Mt], 0, 0, 0);
        }
    }

    // per-row 1/||fe|| with mask folded in; route to output-row lanes via LDS
    #pragma unroll
    for (int Mt = 0; Mt < 4; ++Mt) {
        float t = fss[Mt];
        t += __shfl_xor(t, 16, 64);
        t += __shfl_xor(t, 32, 64);
        int f = Mt * 16 + (l & 15);
        float fn = (f < NFR && fid[Mt] != user_num) ? 1.f : 0.f;
        invL[f] = fn / fmaxf(sqrtf(t), 1e-12f);   // 4 same-value writers, benign
    }
    __builtin_amdgcn_wave_barrier();

    const int m = l & 15;
    if (m < MDIM) {
        float* Ss = Ssum + (size_t)(b & (NSLICE - 1)) * NCOL;
        #pragma unroll
        for (int Mt = 0; Mt < 4; ++Mt) {
            const int fbase = Mt * 16 + (l >> 4) * 4;
            #pragma unroll
            for (int r = 0; r < 4; ++r) {
                int f = fbase + r;
                if (f < NFR) {
                    float val = acc[Mt][r] * invL[f];
                    att_key[((size_t)b * NFR + f) * MDIM + m] = val;
                    // masked rows -> val==0 -> exp(0)=1, matching reference
                    // softmax(axis=0) denominator semantics
                    atomicAdd(&Ss[f * MDIM + m], __expf(val));
                }
            }
        }
    }
}

// k2b: merge NSLICE partials per column -> inv denominator
__global__ __launch_bounds__(256)
void k2b_merge(const float* __restrict__ Ssum, float* __restrict__ ise)
{
    int col = blockIdx.x * 256 + threadIdx.x;
    if (col >= NCOL) return;
    float S = 0.f;
    #pragma unroll
    for (int s = 0; s < NSLICE; ++s) S += Ssum[s * NCOL + col];
    ise[col] = 1.0f / S;
}

// k3: wave-per-b, barrier-free (R2-proven). am -> f2 frag -> 64 MFMAs ->
// fold -> j -> friend sum -> score. All reductions in-wave; LDS slices per-wave.
__global__ __launch_bounds__(256, 2)
void k3_final(const int* __restrict__ input_u, const int* __restrict__ input_i,
              const int* __restrict__ input_uf, const float* __restrict__ uidW,
              const float* __restrict__ iidW, const float* __restrict__ i_bias,
              const float* __restrict__ Mem, const short* __restrict__ WAfrag,
              const float* __restrict__ BA, const float* __restrict__ U_omega,
              const float* __restrict__ att_key, const float* __restrict__ ise,
              float* __restrict__ out, int user_num, int B)
{
    __shared__ short f2F4[4][64 * EDIM];   // 64 KB
    __shared__ float amL4[4][NCOL];        // 6.25 KB
    __shared__ float jxL4[4][64];          // 1 KB
    const int w = threadIdx.x >> 6, l = threadIdx.x & 63;
    const int b = blockIdx.x * 4 + w;
    if (b >= B) return;
    short* f2F = f2F4[w];
    float* amL = amL4[w];
    float* jxL = jxL4[w];

    const int u = input_u[b];
    const int ii = input_i[b];
    const float ib = i_bias[ii];
    int ufv = (l < NFR) ? input_uf[(size_t)b * NFR + l] : user_num;

    const int kg = l & 15, fl = l >> 4;
    const int e0 = kg * 8;

    // am = fn * exp(att_key) * ise  (max-free)
    #pragma unroll
    for (int c = 0; c < 7; ++c) {
        int i = l + 64 * c;
        if (i < NCOL) {
            float ak = att_key[(size_t)b * NCOL + i];
            int fid = __shfl(ufv, i >> 3, 64);
            amL[i] = (fid != user_num) ? __expf(ak) * ise[i] : 0.f;
        }
    }

    float4 mA[MDIM], mB[MDIM];            // Mem slice for this lane's e-octet
    #pragma unroll
    for (int m = 0; m < MDIM; ++m) {
        mA[m] = *(const float4*)&Mem[m * EDIM + e0];
        mB[m] = *(const float4*)&Mem[m * EDIM + e0 + 4];
    }
    __builtin_amdgcn_wave_barrier();

    // phase 1: f2 = (am x Mem) * fe -> swizzled frag (all 64 rows written)
    #pragma unroll 4
    for (int it = 0; it < 16; ++it) {
        int f = fl + 4 * it;
        short8 outv = {0, 0, 0, 0, 0, 0, 0, 0};
        if (f < NFR) {
            int fid = __shfl(ufv, f, 64);
            const float* fp = uidW + (size_t)fid * EDIM + e0;
            float4 g0 = *(const float4*)fp;
            float4 g1 = *(const float4*)(fp + 4);
            float4 am0 = *(const float4*)&amL[f * 8];
            float4 am1 = *(const float4*)&amL[f * 8 + 4];
            float4 fa = {0.f, 0.f, 0.f, 0.f}, fb = {0.f, 0.f, 0.f, 0.f};
            #pragma unroll
            for (int m = 0; m < 4; ++m) {
                float c0 = (&am0.x)[m], c1 = (&am1.x)[m];
                fa.x += c0 * mA[m].x + c1 * mA[m + 4].x;
                fa.y += c0 * mA[m].y + c1 * mA[m + 4].y;
                fa.z += c0 * mA[m].z + c1 * mA[m + 4].z;
                fa.w += c0 * mA[m].w + c1 * mA[m + 4].w;
                fb.x += c0 * mB[m].x + c1 * mB[m + 4].x;
                fb.y += c0 * mB[m].y + c1 * mB[m + 4].y;
                fb.z += c0 * mB[m].z + c1 * mB[m + 4].z;
                fb.w += c0 * mB[m].w + c1 * mB[m + 4].w;
            }
            // masked friends: am==0 -> fa=fb=0 -> f2=0 (matches reference)
            outv[0] = f2bf(fa.x * g0.x);
            outv[1] = f2bf(fa.y * g0.y);
            outv[2] = f2bf(fa.z * g0.z);
            outv[3] = f2bf(fa.w * g0.w);
            outv[4] = f2bf(fb.x * g1.x);
            outv[5] = f2bf(fb.y * g1.y);
            outv[6] = f2bf(fb.z * g1.z);
            outv[7] = f2bf(fb.w * g1.w);
        }
        *(short8*)&f2F[fragOff(f, e0)] = outv;
    }
    __builtin_amdgcn_wave_barrier();

    // phase 2: h = f2(64x128) x WA(128x64), 64 MFMAs per wave
    const int sl = slotR(l);
    f32x4 acc[4][4];
    #pragma unroll
    for (int Mt = 0; Mt < 4; ++Mt)
        #pragma unroll
        for (int Nt = 0; Nt < 4; ++Nt) acc[Mt][Nt] = (f32x4){0.f, 0.f, 0.f, 0.f};
    #pragma unroll
    for (int Kt = 0; Kt < 4; ++Kt) {
        short8 a[4];
        #pragma unroll
        for (int Mt = 0; Mt < 4; ++Mt)
            a[Mt] = *(const short8*)&f2F[(((Mt << 2) | Kt) * 64 + sl) * 8];
        #pragma unroll
        for (int Nt = 0; Nt < 4; ++Nt) {
            short8 bf = *(const short8*)(WAfrag + (size_t)(((Nt << 2) | Kt) * 64 + l) * 8);
            #pragma unroll
            for (int Mt = 0; Mt < 4; ++Mt)
                acc[Mt][Nt] = __builtin_amdgcn_mfma_f32_16x16x32_bf16(a[Mt], bf, acc[Mt][Nt], 0, 0, 0);
        }
    }

    // phase 3: fold relu(h+BA)*U_omega over all 64 cols -> per-friend p
    float ba4[4], uo4[4];
    #pragma unroll
    for (int Nt = 0; Nt < 4; ++Nt) {
        ba4[Nt] = BA[Nt * 16 + kg];
        uo4[Nt] = U_omega[Nt * 16 + kg];
    }
    float v[16];
    #pragma unroll
    for (int Mt = 0; Mt < 4; ++Mt)
        #pragma unroll
        for (int r = 0; r < 4; ++r) {
            float sv = 0.f;
            #pragma unroll
            for (int Nt = 0; Nt < 4; ++Nt)
                sv += fmaxf(acc[Mt][Nt][r] + ba4[Nt], 0.f) * uo4[Nt];
            v[Mt * 4 + r] = sv;
        }

    const bool c0 = l & 1, c1 = l & 2, c2 = l & 4, c3 = l & 8;
    #pragma unroll
    for (int k = 0; k < 8; ++k) {
        float lo = v[k], hi = v[k + 8];
        float send = c0 ? lo : hi;
        float recv = __shfl_xor(send, 1, 64);
        v[k] = c0 ? (hi + recv) : (lo + recv);
    }
    #pragma unroll
    for (int k = 0; k < 4; ++k) {
        float lo = v[k], hi = v[k + 4];
        float send = c1 ? lo : hi;
        float recv = __shfl_xor(send, 2, 64);
        v[k] = c1 ? (hi + recv) : (lo + recv);
    }
    #pragma unroll
    for (int k = 0; k < 2; ++k) {
        float lo = v[k], hi = v[k + 2];
        float send = c2 ? lo : hi;
        float recv = __shfl_xor(send, 4, 64);
        v[k] = c2 ? (hi + recv) : (lo + recv);
    }
    {
        float lo = v[0], hi = v[1];
        float send = c3 ? lo : hi;
        float recv = __shfl_xor(send, 8, 64);
        v[0] = c3 ? (hi + recv) : (lo + recv);
    }
    const int vIdx = ((l & 1) << 3) | ((l & 2) << 1) | ((l & 4) >> 1) | ((l & 8) >> 3);
    const int fLane = (vIdx >> 2) * 16 + (l >> 4) * 4 + (vIdx & 3);

    int ufF = __shfl(ufv, fLane, 64);
    float jv = 0.f;
    if (fLane < NFR && ufF != user_num) jv = __expf(v[0]);
    jxL[fLane] = jv;
    float winv = 1.0f / (waveReduceSum(jv) + 1e-8f);
    __builtin_amdgcn_wave_barrier();

    // phase 4: friend-weighted sum of f2 (pad rows are zero, jx pad = 0)
    float pa[8] = {0.f, 0.f, 0.f, 0.f, 0.f, 0.f, 0.f, 0.f};
    #pragma unroll 4
    for (int it = 0; it < 16; ++it) {
        int f = fl + 4 * it;
        float jf = jxL[f];
        short8 vv = *(const short8*)&f2F[fragOff(f, e0)];
        #pragma unroll
        for (int j = 0; j < 8; ++j) pa[j] += jf * bf2f(vv[j]);
    }
    #pragma unroll
    for (int j = 0; j < 8; ++j) {
        pa[j] += __shfl_xor(pa[j], 16, 64);
        pa[j] += __shfl_xor(pa[j], 32, 64);
    }

    // epilogue: score = sum_e (uid+friend)*iid + i_bias (4x duplicated -> *0.25)
    const float* up = uidW + (size_t)u * EDIM + e0;
    const float* ip = iidW + (size_t)ii * EDIM + e0;
    float4 u0 = *(const float4*)up;
    float4 u1 = *(const float4*)(up + 4);
    float4 i0 = *(const float4*)ip;
    float4 i1 = *(const float4*)(ip + 4);
    float sc = 0.f;
    #pragma unroll
    for (int j = 0; j < 4; ++j) {
        sc += ((&u0.x)[j] + pa[j] * winv) * (&i0.x)[j];
        sc += ((&u1.x)[j] + pa[j + 4] * winv) * (&i1.x)[j];
    }
    float red = waveReduceSum(sc);
    if (l == 0) out[b] = red * 0.25f + ib;
}

extern "C" void kernel_launch(void* const* d_in, const int* in_sizes, int n_in,
                              void* d_out, int out_size, void* d_ws, size_t ws_size,
                              hipStream_t stream)
{
    const int*   input_u  = (const int*)d_in[0];
    const int*   input_i  = (const int*)d_in[1];
    const int*   input_uf = (const int*)d_in[2];
    const float* uidW     = (const float*)d_in[3];
    const float* iidW     = (const float*)d_in[4];
    const float* i_bias   = (const float*)d_in[5];
    const float* Key      = (const float*)d_in[6];
    const float* Mem      = (const float*)d_in[7];
    const float* WA       = (const float*)d_in[8];
    const float* BA       = (const float*)d_in[9];
    const float* U_om     = (const float*)d_in[10];

    const int B = in_sizes[0];
    const int user_num = in_sizes[3] / EDIM - 1;

    float* att  = (float*)d_ws;                                  // B*400
    float* Ssum = att + (size_t)B * NCOL;                        // 64*400
    float* ise  = Ssum + NSLICE * NCOL;                          // 400
    short* WAfrag  = (short*)(ise + NCOL);                       // 8192
    short* Keyfrag = WAfrag + 4 * 4 * 64 * 8;                    // 2048

    const int nb = (B + 3) / 4;
    k0_prep<<<5, 256, 0, stream>>>(WA, Key, WAfrag, Keyfrag, Ssum);
    k1_attkey<<<B, 64, 0, stream>>>(input_u, input_uf, uidW, Keyfrag, att,
                                    Ssum, user_num);
    k2b_merge<<<2, 256, 0, stream>>>(Ssum, ise);
    k3_final<<<nb, 256, 0, stream>>>(input_u, input_i, input_uf, uidW, iidW, i_bias,
                                     Mem, WAfrag, BA, U_om, att, ise,
                                     (float*)d_out, user_num, B);
}

// Round 6
// 168.603 us; speedup vs baseline: 1.2056x; 1.0261x over previous
//
#include <hip/hip_runtime.h>
#include <hip/hip_bf16.h>

#define EDIM 128
#define MDIM 8
#define ADIM 64
#define NFR  50
#define NCOL (NFR * MDIM)   // 400
#define NSLICE 64           // contention slices for softmax denominator atomics

typedef __attribute__((ext_vector_type(8))) short short8;
typedef __attribute__((ext_vector_type(4))) float f32x4;
typedef __attribute__((ext_vector_type(4))) unsigned uint4v;

__device__ __forceinline__ float waveReduceSum(float v) {
    #pragma unroll
    for (int s = 32; s >= 1; s >>= 1) v += __shfl_xor(v, s, 64);
    return v;
}
// packed f32->bf16 (RNE): compiler emits v_cvt_pk_bf16_f32
__device__ __forceinline__ unsigned cvt2u(float lo, float hi) {
    union { __hip_bfloat162 h; unsigned u; } cv;
    cv.h = __float22bfloat162_rn(float2{lo, hi});
    return cv.u;
}
__device__ __forceinline__ short8 pack8(float4 a, float4 b) {
    union { uint4v u; short8 s; } cv;
    cv.u[0] = cvt2u(a.x, a.y);
    cv.u[1] = cvt2u(a.z, a.w);
    cv.u[2] = cvt2u(b.x, b.y);
    cv.u[3] = cvt2u(b.z, b.w);
    return cv.s;
}
__device__ __forceinline__ short f2bf(float x) {
    unsigned u = __float_as_uint(x);
    u += 0x7FFFu + ((u >> 16) & 1u);
    return (short)(u >> 16);
}
__device__ __forceinline__ float bf2f(short s) {
    return __uint_as_float(((unsigned)(unsigned short)s) << 16);
}
// Swizzled A-frag layout (k3 only). Block (Mt=r>>4, Kt=e>>5) of 512 shorts;
// within it slot = (q*16+(r&15)) ^ (q<<1), q=(e>>3)&3.
__device__ __forceinline__ int fragOff(int r, int e) {   // e multiple of 8
    int q = (e >> 3) & 3;
    int slot = (q * 16 + (r & 15)) ^ (q << 1);
    int block = ((r >> 4) << 2) | (e >> 5);
    return (block * 64 + slot) * 8;
}
__device__ __forceinline__ int slotR(int l) { return l ^ (((l >> 4) & 3) << 1); }

// k0: pre-pack WA (B-frags 4Nt x 4Kt) and Key (4Kt, N padded 8->16 with 0);
// also zero the softmax-denominator slices (harness poisons ws each iter).
__global__ __launch_bounds__(256)
void k0_prep(const float* __restrict__ WA, const float* __restrict__ Key,
             short* __restrict__ WAfrag, short* __restrict__ Keyfrag,
             float* __restrict__ Ssum)
{
    int t = blockIdx.x * 256 + threadIdx.x;
    for (int i = t; i < NSLICE * NCOL; i += 5 * 256) Ssum[i] = 0.f;
    if (t < 1024) {
        int lane = t & 63;
        int Kt = (t >> 6) & 3;
        int Nt = t >> 8;
        int n  = Nt * 16 + (lane & 15);
        int k0 = Kt * 32 + (lane >> 4) * 8;
        short8 v;
        #pragma unroll
        for (int j = 0; j < 8; ++j) v[j] = f2bf(WA[(size_t)(k0 + j) * ADIM + n]);
        *(short8*)(WAfrag + (size_t)t * 8) = v;
    } else if (t < 1280) {
        int i = t - 1024;
        int lane = i & 63;
        int Kt = i >> 6;
        int n  = lane & 15;
        int k0 = Kt * 32 + (lane >> 4) * 8;
        short8 v;
        #pragma unroll
        for (int j = 0; j < 8; ++j)
            v[j] = (n < MDIM) ? f2bf(Key[(size_t)(k0 + j) * MDIM + n]) : (short)0;
        *(short8*)(Keyfrag + (size_t)i * 8) = v;
    }
}

// k1: one wave per b, ZERO staging LDS. A-frag = raw fe (bf16, cvt_pk) gathered
// per-lane directly into registers; uid_n folded into B (Key'); 1/||fe|| and
// the friend mask applied to the MFMA OUTPUT rows. No barriers, ~0.75KB LDS.
__global__ __launch_bounds__(64)
void k1_attkey(const int* __restrict__ input_u, const int* __restrict__ input_uf,
               const float* __restrict__ uidW, const short* __restrict__ Keyfrag,
               float* __restrict__ att_key, float* __restrict__ Ssum,
               int user_num)
{
    __shared__ float uidn[EDIM];   // 512 B
    __shared__ float invL[64];     // 256 B
    const int l = threadIdx.x;
    const int b = blockIdx.x;

    const int u = input_u[b];
    int ufv = (l < NFR) ? input_uf[(size_t)b * NFR + l] : user_num;
    float x0 = uidW[(size_t)u * EDIM + l];
    float x1 = uidW[(size_t)u * EDIM + 64 + l];

    // friend ids for my 4 A-frag rows: f = Mt*16 + (l&15)
    // (rows 50..63 resolve to the zero-padded uidW row user_num; their MFMA
    //  output rows are discarded, so garbage there is harmless)
    int fid[4];
    #pragma unroll
    for (int Mt = 0; Mt < 4; ++Mt)
        fid[Mt] = __shfl(ufv, Mt * 16 + (l & 15), 64);
    const int eo = (l >> 4) * 8;    // my k-octet within each 32-wide K block

    // uid L2-normalize (independent of the gathers; overlaps with them)
    float s = waveReduceSum(x0 * x0 + x1 * x1);
    float uinv = 1.0f / fmaxf(sqrtf(s), 1e-12f);
    uidn[l] = x0 * uinv;
    uidn[64 + l] = x1 * uinv;
    __builtin_amdgcn_wave_barrier();

    f32x4 acc[4];
    #pragma unroll
    for (int Mt = 0; Mt < 4; ++Mt) acc[Mt] = (f32x4){0.f, 0.f, 0.f, 0.f};
    float fss[4] = {0.f, 0.f, 0.f, 0.f};

    #pragma unroll
    for (int Kt = 0; Kt < 4; ++Kt) {
        // gather my 4 rows' e-octets for this K block (8 b128 loads in flight)
        float4 ga[4], gb[4];
        #pragma unroll
        for (int Mt = 0; Mt < 4; ++Mt) {
            const float* fp = uidW + (size_t)fid[Mt] * EDIM + Kt * 32 + eo;
            ga[Mt] = *(const float4*)fp;
            gb[Mt] = *(const float4*)(fp + 4);
        }
        // B-frag: Key' = uid_n * Key for my k-octet
        short8 kb = *(const short8*)(Keyfrag + (size_t)(Kt * 64 + l) * 8);
        float4 un0 = *(const float4*)&uidn[Kt * 32 + eo];
        float4 un1 = *(const float4*)&uidn[Kt * 32 + eo + 4];
        float4 kpa, kpb;
        kpa.x = un0.x * bf2f(kb[0]); kpa.y = un0.y * bf2f(kb[1]);
        kpa.z = un0.z * bf2f(kb[2]); kpa.w = un0.w * bf2f(kb[3]);
        kpb.x = un1.x * bf2f(kb[4]); kpb.y = un1.y * bf2f(kb[5]);
        kpb.z = un1.z * bf2f(kb[6]); kpb.w = un1.w * bf2f(kb[7]);
        short8 kbp = pack8(kpa, kpb);
        #pragma unroll
        for (int Mt = 0; Mt < 4; ++Mt) {
            fss[Mt] += ga[Mt].x*ga[Mt].x + ga[Mt].y*ga[Mt].y
                     + ga[Mt].z*ga[Mt].z + ga[Mt].w*ga[Mt].w
                     + gb[Mt].x*gb[Mt].x + gb[Mt].y*gb[Mt].y
                     + gb[Mt].z*gb[Mt].z + gb[Mt].w*gb[Mt].w;
            short8 a = pack8(ga[Mt], gb[Mt]);
            acc[Mt] = __builtin_amdgcn_mfma_f32_16x16x32_bf16(a, kbp, acc[Mt], 0, 0, 0);
        }
    }

    // per-row 1/||fe|| with mask folded in; route to output-row lanes via LDS
    #pragma unroll
    for (int Mt = 0; Mt < 4; ++Mt) {
        float t = fss[Mt];
        t += __shfl_xor(t, 16, 64);
        t += __shfl_xor(t, 32, 64);
        int f = Mt * 16 + (l & 15);
        float fn = (f < NFR && fid[Mt] != user_num) ? 1.f : 0.f;
        invL[f] = fn / fmaxf(sqrtf(t), 1e-12f);   // 4 same-value writers, benign
    }
    __builtin_amdgcn_wave_barrier();

    const int m = l & 15;
    if (m < MDIM) {
        float* Ss = Ssum + (size_t)(b & (NSLICE - 1)) * NCOL;
        #pragma unroll
        for (int Mt = 0; Mt < 4; ++Mt) {
            const int fbase = Mt * 16 + (l >> 4) * 4;
            #pragma unroll
            for (int r = 0; r < 4; ++r) {
                int f = fbase + r;
                if (f < NFR) {
                    float val = acc[Mt][r] * invL[f];
                    att_key[((size_t)b * NFR + f) * MDIM + m] = val;
                    // masked rows -> val==0 -> exp(0)=1, matching reference
                    // softmax(axis=0) denominator semantics
                    atomicAdd(&Ss[f * MDIM + m], __expf(val));
                }
            }
        }
    }
}

// k2b: merge NSLICE partials per column -> inv denominator
__global__ __launch_bounds__(256)
void k2b_merge(const float* __restrict__ Ssum, float* __restrict__ ise)
{
    int col = blockIdx.x * 256 + threadIdx.x;
    if (col >= NCOL) return;
    float S = 0.f;
    #pragma unroll
    for (int s = 0; s < NSLICE; ++s) S += Ssum[s * NCOL + col];
    ise[col] = 1.0f / S;
}

// k3: wave-per-b, barrier-free. am -> f2 frag -> 64 MFMAs -> fold -> j ->
// friend sum -> score. Conversions via cvt_pk; phase-1/4 loops split hi/lo so
// all LDS offsets are affine (const-folded swizzle math).
__global__ __launch_bounds__(256, 2)
void k3_final(const int* __restrict__ input_u, const int* __restrict__ input_i,
              const int* __restrict__ input_uf, const float* __restrict__ uidW,
              const float* __restrict__ iidW, const float* __restrict__ i_bias,
              const float* __restrict__ Mem, const short* __restrict__ WAfrag,
              const float* __restrict__ BA, const float* __restrict__ U_omega,
              const float* __restrict__ att_key, const float* __restrict__ ise,
              float* __restrict__ out, int user_num, int B)
{
    __shared__ short f2F4[4][64 * EDIM];   // 64 KB
    __shared__ float amL4[4][NCOL];        // 6.25 KB
    __shared__ float jxL4[4][64];          // 1 KB
    const int w = threadIdx.x >> 6, l = threadIdx.x & 63;
    const int b = blockIdx.x * 4 + w;
    if (b >= B) return;
    short* f2F = f2F4[w];
    float* amL = amL4[w];
    float* jxL = jxL4[w];

    const int u = input_u[b];
    const int ii = input_i[b];
    const float ib = i_bias[ii];
    int ufv = (l < NFR) ? input_uf[(size_t)b * NFR + l] : user_num;

    const int kg = l & 15, fl = l >> 4;
    const int e0 = kg * 8;

    // am = fn * exp(att_key) * ise  (max-free)
    #pragma unroll
    for (int c = 0; c < 7; ++c) {
        int i = l + 64 * c;
        if (i < NCOL) {
            float ak = att_key[(size_t)b * NCOL + i];
            int fid = __shfl(ufv, i >> 3, 64);
            amL[i] = (fid != user_num) ? __expf(ak) * ise[i] : 0.f;
        }
    }

    float4 mA[MDIM], mB[MDIM];            // Mem slice for this lane's e-octet
    #pragma unroll
    for (int m = 0; m < MDIM; ++m) {
        mA[m] = *(const float4*)&Mem[m * EDIM + e0];
        mB[m] = *(const float4*)&Mem[m * EDIM + e0 + 4];
    }
    __builtin_amdgcn_wave_barrier();

    // phase 1: f2 = (am x Mem) * fe -> swizzled frag (all 64 rows written)
    // f = 16*hi + 4*lo + fl; per-(hi,lo) affine LDS offsets
    #pragma unroll
    for (int hi = 0; hi < 4; ++hi) {
        #pragma unroll
        for (int lo = 0; lo < 4; ++lo) {
            int f = hi * 16 + lo * 4 + fl;
            short8 outv = {0, 0, 0, 0, 0, 0, 0, 0};
            if (f < NFR) {
                int fid = __shfl(ufv, f, 64);
                const float* fp = uidW + (size_t)fid * EDIM + e0;
                float4 g0 = *(const float4*)fp;
                float4 g1 = *(const float4*)(fp + 4);
                float4 am0 = *(const float4*)&amL[f * 8];
                float4 am1 = *(const float4*)&amL[f * 8 + 4];
                float4 fa = {0.f, 0.f, 0.f, 0.f}, fb = {0.f, 0.f, 0.f, 0.f};
                #pragma unroll
                for (int m = 0; m < 4; ++m) {
                    float c0 = (&am0.x)[m], c1 = (&am1.x)[m];
                    fa.x += c0 * mA[m].x + c1 * mA[m + 4].x;
                    fa.y += c0 * mA[m].y + c1 * mA[m + 4].y;
                    fa.z += c0 * mA[m].z + c1 * mA[m + 4].z;
                    fa.w += c0 * mA[m].w + c1 * mA[m + 4].w;
                    fb.x += c0 * mB[m].x + c1 * mB[m + 4].x;
                    fb.y += c0 * mB[m].y + c1 * mB[m + 4].y;
                    fb.z += c0 * mB[m].z + c1 * mB[m + 4].z;
                    fb.w += c0 * mB[m].w + c1 * mB[m + 4].w;
                }
                // masked friends: am==0 -> fa=fb=0 -> f2=0 (matches reference)
                float4 pA, pB;
                pA.x = fa.x * g0.x; pA.y = fa.y * g0.y;
                pA.z = fa.z * g0.z; pA.w = fa.w * g0.w;
                pB.x = fb.x * g1.x; pB.y = fb.y * g1.y;
                pB.z = fb.z * g1.z; pB.w = fb.w * g1.w;
                outv = pack8(pA, pB);
            }
            *(short8*)&f2F[fragOff(f, e0)] = outv;
        }
    }
    __builtin_amdgcn_wave_barrier();

    // phase 2: h = f2(64x128) x WA(128x64), 64 MFMAs per wave
    const int sl = slotR(l);
    f32x4 acc[4][4];
    #pragma unroll
    for (int Mt = 0; Mt < 4; ++Mt)
        #pragma unroll
        for (int Nt = 0; Nt < 4; ++Nt) acc[Mt][Nt] = (f32x4){0.f, 0.f, 0.f, 0.f};
    #pragma unroll
    for (int Kt = 0; Kt < 4; ++Kt) {
        short8 a[4];
        #pragma unroll
        for (int Mt = 0; Mt < 4; ++Mt)
            a[Mt] = *(const short8*)&f2F[(((Mt << 2) | Kt) * 64 + sl) * 8];
        #pragma unroll
        for (int Nt = 0; Nt < 4; ++Nt) {
            short8 bf = *(const short8*)(WAfrag + (size_t)(((Nt << 2) | Kt) * 64 + l) * 8);
            #pragma unroll
            for (int Mt = 0; Mt < 4; ++Mt)
                acc[Mt][Nt] = __builtin_amdgcn_mfma_f32_16x16x32_bf16(a[Mt], bf, acc[Mt][Nt], 0, 0, 0);
        }
    }

    // phase 3: fold relu(h+BA)*U_omega over all 64 cols -> per-friend p
    float ba4[4], uo4[4];
    #pragma unroll
    for (int Nt = 0; Nt < 4; ++Nt) {
        ba4[Nt] = BA[Nt * 16 + kg];
        uo4[Nt] = U_omega[Nt * 16 + kg];
    }
    float v[16];
    #pragma unroll
    for (int Mt = 0; Mt < 4; ++Mt)
        #pragma unroll
        for (int r = 0; r < 4; ++r) {
            float sv = 0.f;
            #pragma unroll
            for (int Nt = 0; Nt < 4; ++Nt)
                sv += fmaxf(acc[Mt][Nt][r] + ba4[Nt], 0.f) * uo4[Nt];
            v[Mt * 4 + r] = sv;
        }

    const bool c0 = l & 1, c1 = l & 2, c2 = l & 4, c3 = l & 8;
    #pragma unroll
    for (int k = 0; k < 8; ++k) {
        float lo = v[k], hi = v[k + 8];
        float send = c0 ? lo : hi;
        float recv = __shfl_xor(send, 1, 64);
        v[k] = c0 ? (hi + recv) : (lo + recv);
    }
    #pragma unroll
    for (int k = 0; k < 4; ++k) {
        float lo = v[k], hi = v[k + 4];
        float send = c1 ? lo : hi;
        float recv = __shfl_xor(send, 2, 64);
        v[k] = c1 ? (hi + recv) : (lo + recv);
    }
    #pragma unroll
    for (int k = 0; k < 2; ++k) {
        float lo = v[k], hi = v[k + 2];
        float send = c2 ? lo : hi;
        float recv = __shfl_xor(send, 4, 64);
        v[k] = c2 ? (hi + recv) : (lo + recv);
    }
    {
        float lo = v[0], hi = v[1];
        float send = c3 ? lo : hi;
        float recv = __shfl_xor(send, 8, 64);
        v[0] = c3 ? (hi + recv) : (lo + recv);
    }
    const int vIdx = ((l & 1) << 3) | ((l & 2) << 1) | ((l & 4) >> 1) | ((l & 8) >> 3);
    const int fLane = (vIdx >> 2) * 16 + (l >> 4) * 4 + (vIdx & 3);

    int ufF = __shfl(ufv, fLane, 64);
    float jv = 0.f;
    if (fLane < NFR && ufF != user_num) jv = __expf(v[0]);
    jxL[fLane] = jv;
    float winv = 1.0f / (waveReduceSum(jv) + 1e-8f);
    __builtin_amdgcn_wave_barrier();

    // phase 4: friend-weighted sum of f2 (pad rows are zero, jx pad = 0)
    float pa[8] = {0.f, 0.f, 0.f, 0.f, 0.f, 0.f, 0.f, 0.f};
    #pragma unroll
    for (int hi = 0; hi < 4; ++hi) {
        #pragma unroll
        for (int lo = 0; lo < 4; ++lo) {
            int f = hi * 16 + lo * 4 + fl;
            float jf = jxL[f];
            short8 vv = *(const short8*)&f2F[fragOff(f, e0)];
            #pragma unroll
            for (int j = 0; j < 8; ++j) pa[j] += jf * bf2f(vv[j]);
        }
    }
    #pragma unroll
    for (int j = 0; j < 8; ++j) {
        pa[j] += __shfl_xor(pa[j], 16, 64);
        pa[j] += __shfl_xor(pa[j], 32, 64);
    }

    // epilogue: score = sum_e (uid+friend)*iid + i_bias (4x duplicated -> *0.25)
    const float* up = uidW + (size_t)u * EDIM + e0;
    const float* ip = iidW + (size_t)ii * EDIM + e0;
    float4 u0 = *(const float4*)up;
    float4 u1 = *(const float4*)(up + 4);
    float4 i0 = *(const float4*)ip;
    float4 i1 = *(const float4*)(ip + 4);
    float sc = 0.f;
    #pragma unroll
    for (int j = 0; j < 4; ++j) {
        sc += ((&u0.x)[j] + pa[j] * winv) * (&i0.x)[j];
        sc += ((&u1.x)[j] + pa[j + 4] * winv) * (&i1.x)[j];
    }
    float red = waveReduceSum(sc);
    if (l == 0) out[b] = red * 0.25f + ib;
}

extern "C" void kernel_launch(void* const* d_in, const int* in_sizes, int n_in,
                              void* d_out, int out_size, void* d_ws, size_t ws_size,
                              hipStream_t stream)
{
    const int*   input_u  = (const int*)d_in[0];
    const int*   input_i  = (const int*)d_in[1];
    const int*   input_uf = (const int*)d_in[2];
    const float* uidW     = (const float*)d_in[3];
    const float* iidW     = (const float*)d_in[4];
    const float* i_bias   = (const float*)d_in[5];
    const float* Key      = (const float*)d_in[6];
    const float* Mem      = (const float*)d_in[7];
    const float* WA       = (const float*)d_in[8];
    const float* BA       = (const float*)d_in[9];
    const float* U_om     = (const float*)d_in[10];

    const int B = in_sizes[0];
    const int user_num = in_sizes[3] / EDIM - 1;

    float* att  = (float*)d_ws;                                  // B*400
    float* Ssum = att + (size_t)B * NCOL;                        // 64*400
    float* ise  = Ssum + NSLICE * NCOL;                          // 400
    short* WAfrag  = (short*)(ise + NCOL);                       // 8192
    short* Keyfrag = WAfrag + 4 * 4 * 64 * 8;                    // 2048

    const int nb = (B + 3) / 4;
    k0_prep<<<5, 256, 0, stream>>>(WA, Key, WAfrag, Keyfrag, Ssum);
    k1_attkey<<<B, 64, 0, stream>>>(input_u, input_uf, uidW, Keyfrag, att,
                                    Ssum, user_num);
    k2b_merge<<<2, 256, 0, stream>>>(Ssum, ise);
    k3_final<<<nb, 256, 0, stream>>>(input_u, input_i, input_uf, uidW, iidW, i_bias,
                                     Mem, WAfrag, BA, U_om, att, ise,
                                     (float*)d_out, user_num, B);
}